// Round 12
// baseline (225.397 us; speedup 1.0000x reference)
//
#include <hip/hip_runtime.h>
#include <stdint.h>
#include <math.h>

#define NROW 32768
#define MCOL 2048
#define KDIM 128
#define NHEAD 8
#define SCALE 0.08838834764831845f  /* 1/sqrt(128) */

typedef __attribute__((ext_vector_type(8))) short short8;
typedef __attribute__((ext_vector_type(4))) float f32x4;

__device__ __forceinline__ uint32_t rotl32(uint32_t x, uint32_t r) {
  return __builtin_amdgcn_alignbit(x, x, 32u - r);
}

// threefry2x32 with key=(0,42), input (0, c); returns o0 ^ o1 (JAX partitionable 32-bit draw)
__device__ __forceinline__ uint32_t tf_hash(uint32_t c) {
  const uint32_t K2 = 0x1BD11BDAu ^ 0u ^ 42u;
  uint32_t x0 = 0u, x1 = c + 42u;
#define R4A { x0 += x1; x1 = rotl32(x1,13); x1 ^= x0; \
              x0 += x1; x1 = rotl32(x1,15); x1 ^= x0; \
              x0 += x1; x1 = rotl32(x1,26); x1 ^= x0; \
              x0 += x1; x1 = rotl32(x1, 6); x1 ^= x0; }
#define R4B { x0 += x1; x1 = rotl32(x1,17); x1 ^= x0; \
              x0 += x1; x1 = rotl32(x1,29); x1 ^= x0; \
              x0 += x1; x1 = rotl32(x1,16); x1 ^= x0; \
              x0 += x1; x1 = rotl32(x1,24); x1 ^= x0; }
  R4A x0 += 42u;      x1 += K2 + 1u;
  R4B x0 += K2;       x1 += 2u;
  R4A /* x0 += 0 */   x1 += 42u + 3u;
  R4B x0 += 42u;      x1 += K2 + 4u;
  R4A x0 += K2;       x1 += 5u;
#undef R4A
#undef R4B
  return x0 ^ x1;
}

// JAX uniform(minval=tiny, maxval=1) bit path (low 9 bits of b ignored)
__device__ __forceinline__ float bits_to_u(uint32_t b) {
  uint32_t fb = (b >> 9) | 0x3F800000u;
  float f = __uint_as_float(fb) - 1.0f;
  return (f == 0.0f) ? 1.17549435e-38f : f;
}

__device__ __forceinline__ float gumbel_of_key(uint32_t key) {
  float u = bits_to_u(key);
  return -logf(-logf(u));
}

// ---------------- precompute: Wsum, bsum; also zero accum (fused, drops a memset dispatch) ----------------
__global__ void k_wsum(const float* __restrict__ Wq, const float* __restrict__ bq,
                       float* __restrict__ Wsum, float* __restrict__ bsum,
                       float* __restrict__ accum) {
  int t = blockIdx.x * 256 + threadIdx.x;
  if (t < KDIM * KDIM) {
    int d = t >> 7, e = t & 127;
    float s = 0.f;
#pragma unroll
    for (int h = 0; h < NHEAD; ++h) s += Wq[(h * KDIM + d) * KDIM + e];
    Wsum[t] = s;
  }
  // zero accum: 262144 floats / 16384 threads = 4 float4 per thread
  {
    float4 z = {0.f, 0.f, 0.f, 0.f};
    float4* a4 = (float4*)accum;
#pragma unroll
    for (int r = 0; r < 4; ++r) a4[t + r * 16384] = z;
  }
  if (blockIdx.x == 0 && threadIdx.x < KDIM) {
    int d = threadIdx.x;
    float s = 0.f;
#pragma unroll
    for (int h = 0; h < NHEAD; ++h) s += bq[h * KDIM + d];
    bsum[d] = 2.0f * s;
  }
}

// ---------------- precompute: cw_s, cb_s, cwB (bf16 MFMA B-fragments) ----------------
__global__ void k_cw(const float* __restrict__ c, const float* __restrict__ Wsum,
                     const float* __restrict__ bsum,
                     float* __restrict__ cw_s, unsigned short* __restrict__ cwB16,
                     float* __restrict__ cb_s) {
  int m = blockIdx.x;
  int e = threadIdx.x;  // 128 threads
  __shared__ float crow[KDIM];
  if (e < 32) ((float4*)crow)[e] = ((const float4*)(c + (size_t)m * KDIM))[e];
  __syncthreads();
  float s = 0.f;
#pragma unroll 4
  for (int d = 0; d < KDIM; ++d) s += crow[d] * Wsum[d * KDIM + e];
  float sv = s * SCALE;
  cw_s[(size_t)m * KDIM + e] = sv;
  {
    int t = m >> 4, col = m & 15, ks = e >> 5, grp = (e >> 3) & 3, j = e & 7;
    int lane = grp * 16 + col;
    cwB16[(((size_t)(t * 4 + ks)) * 64 + lane) * 8 + j] =
        (unsigned short)(__float_as_uint(sv) >> 16);
  }
  if (e == 0) {
    float sb = 0.f;
    for (int d = 0; d < KDIM; ++d) sb += bsum[d] * crow[d];
    cb_s[m] = sb * SCALE;
  }
}

// ---------------- k_mega: 16 rows/block, 8 blocks/CU, rotated stats role ----------------
// 2048 blocks x 256 threads. Block b owns rows [16b, 16b+16).
// role = (wv + b) & 3  (spreads stats waves across SIMDs):
//   role 0: partial stats ALL 16 rows, column tiles 0..63
//   role 1: partial stats ALL 16 rows, column tiles 64..127
//   roles 2,3: no stats
// Then ALL waves scan 4 rows each (frozen r8 loop); barrier; adjudicate + scatter.
__launch_bounds__(256, 8)
__global__ void k_mega(const float* __restrict__ x1, const float* __restrict__ kin,
                       const uint4* __restrict__ cwB, const float* __restrict__ cb_s,
                       const float* __restrict__ cw_s, float* __restrict__ accum) {
  __shared__ float smx_p[2][16];   // per-half partial row max
  __shared__ float sD_p[2][16];    // per-half partial raw exp-sum
  __shared__ float xksh[4][KDIM];  // fallback-only scratch (2KB)

  const int tid = threadIdx.x;
  const int wv = tid >> 6, lane = tid & 63;
  const int B = blockIdx.x * 16;
  const int role = (wv + (int)blockIdx.x) & 3;
  const int sstart = wv * 4;

  // ================= stats role (2 of the 4 waves, rotated): m-split partials =================
  if (role < 2) {
    const int rowA = B + (lane & 15);
    const int kbase = (lane >> 4) * 8;

    union { uint32_t u[4]; short8 s; } af[4];
#pragma unroll
    for (int ks = 0; ks < 4; ++ks) {
      const float* xp = x1 + (size_t)rowA * KDIM + ks * 32 + kbase;
      const float* kp = kin + (size_t)rowA * KDIM + ks * 32 + kbase;
      float4 a0 = *(const float4*)xp, a1 = *(const float4*)(xp + 4);
      float4 b0 = *(const float4*)kp, b1 = *(const float4*)(kp + 4);
      float f[8] = {a0.x + b0.x, a0.y + b0.y, a0.z + b0.z, a0.w + b0.w,
                    a1.x + b1.x, a1.y + b1.y, a1.z + b1.z, a1.w + b1.w};
#pragma unroll
      for (int r = 0; r < 4; ++r)
        af[ks].u[r] = (__float_as_uint(f[2 * r]) >> 16) |
                      (__float_as_uint(f[2 * r + 1]) & 0xFFFF0000u);
    }

    float mxs[4], Ds[4];
#pragma unroll
    for (int r = 0; r < 4; ++r) { mxs[r] = -INFINITY; Ds[r] = 0.f; }

#pragma unroll 2
    for (int ti = 0; ti < 64; ++ti) {
      const int t = role * 64 + ti;
      f32x4 acc = {0.f, 0.f, 0.f, 0.f};
#pragma unroll
      for (int ks = 0; ks < 4; ++ks) {
        union { uint4 v; short8 s; } bf;
        bf.v = cwB[(size_t)(t * 4 + ks) * 64 + lane];
        acc = __builtin_amdgcn_mfma_f32_16x16x32_bf16(af[ks].s, bf.s, acc, 0, 0, 0);
      }
      float cbv = cb_s[t * 16 + (lane & 15)];
#pragma unroll
      for (int r = 0; r < 4; ++r) {
        float lv = acc[r] + cbv;
        mxs[r] = fmaxf(mxs[r], lv);
        Ds[r] += __expf(lv);
      }
    }

    // reduce over the 16 lanes sharing the same rows
#pragma unroll
    for (int s = 1; s < 16; s <<= 1) {
#pragma unroll
      for (int r = 0; r < 4; ++r) {
        mxs[r] = fmaxf(mxs[r], __shfl_xor(mxs[r], s));
        Ds[r] += __shfl_xor(Ds[r], s);
      }
    }
    if ((lane & 15) == 0) {
#pragma unroll
      for (int r = 0; r < 4; ++r) {
        int lr = (lane >> 4) * 4 + r;
        smx_p[role][lr] = mxs[r];
        sD_p[role][lr] = Ds[r];
      }
    }
  }

  // ===== scan role (all waves): r8 loop FROZEN — single chain, top-3, 4 rows/wave =====
  uint32_t tk0[4], tk1[4], tk2[4];
#pragma unroll
  for (int ri = 0; ri < 4; ++ri) {
    const int n = B + sstart + ri;
    const uint32_t c0 = (uint32_t)n * (uint32_t)MCOL + (uint32_t)lane;
    uint32_t t0 = 0u, t1 = 0u, t2 = 0u;
#pragma unroll 8
    for (uint32_t jj = 0; jj < 32; ++jj) {
      uint32_t b = tf_hash(c0 + 64u * jj);
      uint32_t key = (b & 0xFFFFFE00u) | jj;  // u-bits | jj  (m = lane | jj<<6)
      t2 = max(t2, min(min(t0, t1), key));
      t1 = max(t1, min(t0, key));
      t0 = max(t0, key);
    }
    tk0[ri] = t0; tk1[ri] = t1; tk2[ri] = t2;
  }

  __syncthreads();  // stats partials ready in LDS

  // ================= adjudicate + scatter =================
#pragma unroll 1
  for (int ri = 0; ri < 4; ++ri) {
    const int lr = sstart + ri;
    const int n = B + lr;

    uint32_t t0 = tk0[ri], t1 = tk1[ri], t2 = tk2[ri];
    uint32_t kmax = t0;
#pragma unroll
    for (int s = 1; s < 64; s <<= 1)
      kmax = max(kmax, (uint32_t)__shfl_xor((int)kmax, s));

    // combine the two m-slice partials (raw exp-sums add; maxes max)
    const float mx = fmaxf(smx_p[0][lr], smx_p[1][lr]);
    const float Dp = sD_p[0][lr] + sD_p[1][lr];
    const float pmax = __expf(mx) / Dp;
    const float gstar = gumbel_of_key(kmax);
    const float thr = gstar - (pmax * 1.05f + 2e-4f);

    const float2 xa = ((const float2*)(x1 + (size_t)n * KDIM))[lane];
    const float2 xb = ((const float2*)(kin + (size_t)n * KDIM))[lane];
    const float xk0 = xa.x + xb.x, xk1 = xa.y + xb.y;

    float bestSc = -INFINITY;
    int bestM = 0x7FFFFFFF;

    if (pmax > 0.2f) {
      // -------- exact full-rescan fallback (prob ~0, correctness valve) --------
      xksh[wv][lane * 2] = xk0;
      xksh[wv][lane * 2 + 1] = xk1;
      __builtin_amdgcn_s_waitcnt(0);
      for (uint32_t jj = 0; jj < 32; ++jj) {
        uint32_t m = (uint32_t)lane | (jj << 6);
        uint32_t b = tf_hash((uint32_t)n * (uint32_t)MCOL + m);
        float g = -logf(-logf(bits_to_u(b)));
        float l = 0.f;
        for (int e = 0; e < KDIM; ++e) l += xksh[wv][e] * cw_s[(size_t)m * KDIM + e];
        float p = __expf(l + cb_s[m]) / Dp;
        float sc = p + g;
        if (sc > bestSc || (sc == bestSc && (int)m < bestM)) { bestSc = sc; bestM = (int)m; }
      }
#pragma unroll
      for (int s = 1; s < 64; s <<= 1) {
        float os = __shfl_xor(bestSc, s);
        int om = __shfl_xor(bestM, s);
        if (os > bestSc || (os == bestSc && om < bestM)) { bestSc = os; bestM = om; }
      }
    } else {
      // -------- normal path: adjudicate in-register top-3 candidates --------
#pragma unroll
      for (int s = 0; s < 3; ++s) {
        uint32_t tkv = (s == 0) ? t0 : ((s == 1) ? t1 : t2);
        float g = gumbel_of_key(tkv);
        unsigned long long bl = __ballot(g >= thr);
        while (bl) {
          int src = __ffsll(bl) - 1;
          bl &= bl - 1ull;
          uint32_t kk = (uint32_t)__shfl((int)tkv, src);
          float gc = __shfl(g, src);
          int m = src | (int)((kk & 31u) << 6);
          const float2 cv = ((const float2*)(cw_s + (size_t)m * KDIM))[lane];
          float part = xk0 * cv.x + xk1 * cv.y;
#pragma unroll
          for (int sh = 1; sh < 64; sh <<= 1) part += __shfl_xor(part, sh);
          float p = __expf(part + cb_s[m]) / Dp;
          float sc = p + gc;
          if (sc > bestSc || (sc == bestSc && m < bestM)) { bestSc = sc; bestM = m; }
        }
      }
    }

    float* dst = accum + (size_t)bestM * KDIM + lane * 2;
    atomicAdd(dst + 0, xa.x);
    atomicAdd(dst + 1, xa.y);
  }
}

// ---------------- final: out = accum @ Wd.T + bd ----------------
__global__ void k_final(const float* __restrict__ acc, const float* __restrict__ Wd,
                        const float* __restrict__ bd, float* __restrict__ out) {
  int m = blockIdx.x, j = threadIdx.x;  // 128 threads
  __shared__ float ar[KDIM];
  if (j < 32) ((float4*)ar)[j] = ((const float4*)(acc + (size_t)m * KDIM))[j];
  __syncthreads();
  const float4* wr = (const float4*)(Wd + (size_t)j * KDIM);
  float s = 0.f;
#pragma unroll
  for (int e4 = 0; e4 < 32; ++e4) {
    float4 wv = wr[e4];
    s += wv.x * ar[4 * e4 + 0] + wv.y * ar[4 * e4 + 1]
       + wv.z * ar[4 * e4 + 2] + wv.w * ar[4 * e4 + 3];
  }
  out[(size_t)m * KDIM + j] = s + bd[j];
}

extern "C" void kernel_launch(void* const* d_in, const int* in_sizes, int n_in,
                              void* d_out, int out_size, void* d_ws, size_t ws_size,
                              hipStream_t stream) {
  const float* x1 = (const float*)d_in[0];
  const float* k  = (const float*)d_in[1];
  const float* c  = (const float*)d_in[2];
  const float* Wq = (const float*)d_in[3];
  const float* bq = (const float*)d_in[4];
  const float* Wd = (const float*)d_in[5];
  const float* bd = (const float*)d_in[6];
  float* out = (float*)d_out;

  char* ws = (char*)d_ws;
  size_t off = 0;
  float* cw_s = (float*)(ws + off); off += (size_t)MCOL * KDIM * 4;                   // 1MB
  float* cb_s = (float*)(ws + off); off += 8192;                                      // 8KB
  unsigned short* cwB = (unsigned short*)(ws + off); off += (size_t)MCOL * KDIM * 2;  // 512KB
  float* Wsum = (float*)(ws + off); off += KDIM * KDIM * 4;                           // 64KB
  float* bsum = (float*)(ws + off); off += 4096;
  float* accum = (float*)(ws + off); off += (size_t)MCOL * KDIM * 4;                  // 1MB

  k_wsum<<<64, 256, 0, stream>>>(Wq, bq, Wsum, bsum, accum);
  k_cw<<<MCOL, 128, 0, stream>>>(c, Wsum, bsum, cw_s, cwB, cb_s);
  k_mega<<<2048, 256, 0, stream>>>(x1, k, (const uint4*)cwB, cb_s, cw_s, accum);
  k_final<<<MCOL, 128, 0, stream>>>(accum, Wd, bd, out);
}

// Round 13
// 190.274 us; speedup vs baseline: 1.1846x; 1.1846x over previous
//
#include <hip/hip_runtime.h>
#include <stdint.h>
#include <math.h>

#define NROW 32768
#define MCOL 2048
#define KDIM 128
#define NHEAD 8
#define SCALE 0.08838834764831845f  /* 1/sqrt(128) */

typedef __attribute__((ext_vector_type(8))) short short8;
typedef __attribute__((ext_vector_type(4))) float f32x4;

__device__ __forceinline__ uint32_t rotl32(uint32_t x, uint32_t r) {
  return __builtin_amdgcn_alignbit(x, x, 32u - r);
}

// threefry2x32 with key=(0,42), input (0, c); returns o0 ^ o1 (JAX partitionable 32-bit draw)
__device__ __forceinline__ uint32_t tf_hash(uint32_t c) {
  const uint32_t K2 = 0x1BD11BDAu ^ 0u ^ 42u;
  uint32_t x0 = 0u, x1 = c + 42u;
#define R4A { x0 += x1; x1 = rotl32(x1,13); x1 ^= x0; \
              x0 += x1; x1 = rotl32(x1,15); x1 ^= x0; \
              x0 += x1; x1 = rotl32(x1,26); x1 ^= x0; \
              x0 += x1; x1 = rotl32(x1, 6); x1 ^= x0; }
#define R4B { x0 += x1; x1 = rotl32(x1,17); x1 ^= x0; \
              x0 += x1; x1 = rotl32(x1,29); x1 ^= x0; \
              x0 += x1; x1 = rotl32(x1,16); x1 ^= x0; \
              x0 += x1; x1 = rotl32(x1,24); x1 ^= x0; }
  R4A x0 += 42u;      x1 += K2 + 1u;
  R4B x0 += K2;       x1 += 2u;
  R4A /* x0 += 0 */   x1 += 42u + 3u;
  R4B x0 += 42u;      x1 += K2 + 4u;
  R4A x0 += K2;       x1 += 5u;
#undef R4A
#undef R4B
  return x0 ^ x1;
}

// JAX uniform(minval=tiny, maxval=1) bit path (low 9 bits of b ignored)
__device__ __forceinline__ float bits_to_u(uint32_t b) {
  uint32_t fb = (b >> 9) | 0x3F800000u;
  float f = __uint_as_float(fb) - 1.0f;
  return (f == 0.0f) ? 1.17549435e-38f : f;
}

__device__ __forceinline__ float gumbel_of_key(uint32_t key) {
  float u = bits_to_u(key);
  return -logf(-logf(u));
}

// ---------------- precompute: Wsum, bsum; also zero accum (fused, drops a memset dispatch) ----------------
__global__ void k_wsum(const float* __restrict__ Wq, const float* __restrict__ bq,
                       float* __restrict__ Wsum, float* __restrict__ bsum,
                       float* __restrict__ accum) {
  int t = blockIdx.x * 256 + threadIdx.x;
  if (t < KDIM * KDIM) {
    int d = t >> 7, e = t & 127;
    float s = 0.f;
#pragma unroll
    for (int h = 0; h < NHEAD; ++h) s += Wq[(h * KDIM + d) * KDIM + e];
    Wsum[t] = s;
  }
  // zero accum: 262144 floats / 16384 threads = 4 float4 per thread
  {
    float4 z = {0.f, 0.f, 0.f, 0.f};
    float4* a4 = (float4*)accum;
#pragma unroll
    for (int r = 0; r < 4; ++r) a4[t + r * 16384] = z;
  }
  if (blockIdx.x == 0 && threadIdx.x < KDIM) {
    int d = threadIdx.x;
    float s = 0.f;
#pragma unroll
    for (int h = 0; h < NHEAD; ++h) s += bq[h * KDIM + d];
    bsum[d] = 2.0f * s;
  }
}

// ---------------- precompute: cw_s, cb_s, cwB (bf16 MFMA B-fragments) ----------------
__global__ void k_cw(const float* __restrict__ c, const float* __restrict__ Wsum,
                     const float* __restrict__ bsum,
                     float* __restrict__ cw_s, unsigned short* __restrict__ cwB16,
                     float* __restrict__ cb_s) {
  int m = blockIdx.x;
  int e = threadIdx.x;  // 128 threads
  __shared__ float crow[KDIM];
  if (e < 32) ((float4*)crow)[e] = ((const float4*)(c + (size_t)m * KDIM))[e];
  __syncthreads();
  float s = 0.f;
#pragma unroll 4
  for (int d = 0; d < KDIM; ++d) s += crow[d] * Wsum[d * KDIM + e];
  float sv = s * SCALE;
  cw_s[(size_t)m * KDIM + e] = sv;
  {
    int t = m >> 4, col = m & 15, ks = e >> 5, grp = (e >> 3) & 3, j = e & 7;
    int lane = grp * 16 + col;
    cwB16[(((size_t)(t * 4 + ks)) * 64 + lane) * 8 + j] =
        (unsigned short)(__float_as_uint(sv) >> 16);
  }
  if (e == 0) {
    float sb = 0.f;
    for (int d = 0; d < KDIM; ++d) sb += bsum[d] * crow[d];
    cb_s[m] = sb * SCALE;
  }
}

// ---------------- k_mega: 16 rows/block, rotated stats role, NO register crush ----------------
// 2048 blocks x 256 threads. Block b owns rows [16b, 16b+16).
// role = (wv + b) & 3  (spreads stats waves across SIMDs):
//   role 0: partial stats ALL 16 rows, column tiles 0..63
//   role 1: partial stats ALL 16 rows, column tiles 64..127
//   roles 2,3: no stats
// Then ALL waves scan 4 rows each (frozen r8 loop); barrier; adjudicate + scatter.
// launch_bounds min-waves = 4 (VGPR cap 128): kernel lands ~52 VGPR <= 64,
// so HW still allows 8 waves/SIMD with a 2048-block grid — occupancy without spills.
__launch_bounds__(256, 4)
__global__ void k_mega(const float* __restrict__ x1, const float* __restrict__ kin,
                       const uint4* __restrict__ cwB, const float* __restrict__ cb_s,
                       const float* __restrict__ cw_s, float* __restrict__ accum) {
  __shared__ float smx_p[2][16];   // per-half partial row max
  __shared__ float sD_p[2][16];    // per-half partial raw exp-sum
  __shared__ float xksh[4][KDIM];  // fallback-only scratch (2KB)

  const int tid = threadIdx.x;
  const int wv = tid >> 6, lane = tid & 63;
  const int B = blockIdx.x * 16;
  const int role = (wv + (int)blockIdx.x) & 3;
  const int sstart = wv * 4;

  // ================= stats role (2 of the 4 waves, rotated): m-split partials =================
  if (role < 2) {
    const int rowA = B + (lane & 15);
    const int kbase = (lane >> 4) * 8;

    union { uint32_t u[4]; short8 s; } af[4];
#pragma unroll
    for (int ks = 0; ks < 4; ++ks) {
      const float* xp = x1 + (size_t)rowA * KDIM + ks * 32 + kbase;
      const float* kp = kin + (size_t)rowA * KDIM + ks * 32 + kbase;
      float4 a0 = *(const float4*)xp, a1 = *(const float4*)(xp + 4);
      float4 b0 = *(const float4*)kp, b1 = *(const float4*)(kp + 4);
      float f[8] = {a0.x + b0.x, a0.y + b0.y, a0.z + b0.z, a0.w + b0.w,
                    a1.x + b1.x, a1.y + b1.y, a1.z + b1.z, a1.w + b1.w};
#pragma unroll
      for (int r = 0; r < 4; ++r)
        af[ks].u[r] = (__float_as_uint(f[2 * r]) >> 16) |
                      (__float_as_uint(f[2 * r + 1]) & 0xFFFF0000u);
    }

    float mxs[4], Ds[4];
#pragma unroll
    for (int r = 0; r < 4; ++r) { mxs[r] = -INFINITY; Ds[r] = 0.f; }

#pragma unroll 2
    for (int ti = 0; ti < 64; ++ti) {
      const int t = role * 64 + ti;
      f32x4 acc = {0.f, 0.f, 0.f, 0.f};
#pragma unroll
      for (int ks = 0; ks < 4; ++ks) {
        union { uint4 v; short8 s; } bf;
        bf.v = cwB[(size_t)(t * 4 + ks) * 64 + lane];
        acc = __builtin_amdgcn_mfma_f32_16x16x32_bf16(af[ks].s, bf.s, acc, 0, 0, 0);
      }
      float cbv = cb_s[t * 16 + (lane & 15)];
#pragma unroll
      for (int r = 0; r < 4; ++r) {
        float lv = acc[r] + cbv;
        mxs[r] = fmaxf(mxs[r], lv);
        Ds[r] += __expf(lv);
      }
    }

    // reduce over the 16 lanes sharing the same rows
#pragma unroll
    for (int s = 1; s < 16; s <<= 1) {
#pragma unroll
      for (int r = 0; r < 4; ++r) {
        mxs[r] = fmaxf(mxs[r], __shfl_xor(mxs[r], s));
        Ds[r] += __shfl_xor(Ds[r], s);
      }
    }
    if ((lane & 15) == 0) {
#pragma unroll
      for (int r = 0; r < 4; ++r) {
        int lr = (lane >> 4) * 4 + r;
        smx_p[role][lr] = mxs[r];
        sD_p[role][lr] = Ds[r];
      }
    }
  }

  // ===== scan role (all waves): r8 loop FROZEN — single chain, top-3, 4 rows/wave =====
  uint32_t tk0[4], tk1[4], tk2[4];
#pragma unroll
  for (int ri = 0; ri < 4; ++ri) {
    const int n = B + sstart + ri;
    const uint32_t c0 = (uint32_t)n * (uint32_t)MCOL + (uint32_t)lane;
    uint32_t t0 = 0u, t1 = 0u, t2 = 0u;
#pragma unroll 8
    for (uint32_t jj = 0; jj < 32; ++jj) {
      uint32_t b = tf_hash(c0 + 64u * jj);
      uint32_t key = (b & 0xFFFFFE00u) | jj;  // u-bits | jj  (m = lane | jj<<6)
      t2 = max(t2, min(min(t0, t1), key));
      t1 = max(t1, min(t0, key));
      t0 = max(t0, key);
    }
    tk0[ri] = t0; tk1[ri] = t1; tk2[ri] = t2;
  }

  __syncthreads();  // stats partials ready in LDS

  // ================= adjudicate + scatter =================
#pragma unroll 1
  for (int ri = 0; ri < 4; ++ri) {
    const int lr = sstart + ri;
    const int n = B + lr;

    uint32_t t0 = tk0[ri], t1 = tk1[ri], t2 = tk2[ri];
    uint32_t kmax = t0;
#pragma unroll
    for (int s = 1; s < 64; s <<= 1)
      kmax = max(kmax, (uint32_t)__shfl_xor((int)kmax, s));

    // combine the two m-slice partials (raw exp-sums add; maxes max)
    const float mx = fmaxf(smx_p[0][lr], smx_p[1][lr]);
    const float Dp = sD_p[0][lr] + sD_p[1][lr];
    const float pmax = __expf(mx) / Dp;
    const float gstar = gumbel_of_key(kmax);
    const float thr = gstar - (pmax * 1.05f + 2e-4f);

    const float2 xa = ((const float2*)(x1 + (size_t)n * KDIM))[lane];
    const float2 xb = ((const float2*)(kin + (size_t)n * KDIM))[lane];
    const float xk0 = xa.x + xb.x, xk1 = xa.y + xb.y;

    float bestSc = -INFINITY;
    int bestM = 0x7FFFFFFF;

    if (pmax > 0.2f) {
      // -------- exact full-rescan fallback (prob ~0, correctness valve) --------
      xksh[wv][lane * 2] = xk0;
      xksh[wv][lane * 2 + 1] = xk1;
      __builtin_amdgcn_s_waitcnt(0);
      for (uint32_t jj = 0; jj < 32; ++jj) {
        uint32_t m = (uint32_t)lane | (jj << 6);
        uint32_t b = tf_hash((uint32_t)n * (uint32_t)MCOL + m);
        float g = -logf(-logf(bits_to_u(b)));
        float l = 0.f;
        for (int e = 0; e < KDIM; ++e) l += xksh[wv][e] * cw_s[(size_t)m * KDIM + e];
        float p = __expf(l + cb_s[m]) / Dp;
        float sc = p + g;
        if (sc > bestSc || (sc == bestSc && (int)m < bestM)) { bestSc = sc; bestM = (int)m; }
      }
#pragma unroll
      for (int s = 1; s < 64; s <<= 1) {
        float os = __shfl_xor(bestSc, s);
        int om = __shfl_xor(bestM, s);
        if (os > bestSc || (os == bestSc && om < bestM)) { bestSc = os; bestM = om; }
      }
    } else {
      // -------- normal path: adjudicate in-register top-3 candidates --------
#pragma unroll
      for (int s = 0; s < 3; ++s) {
        uint32_t tkv = (s == 0) ? t0 : ((s == 1) ? t1 : t2);
        float g = gumbel_of_key(tkv);
        unsigned long long bl = __ballot(g >= thr);
        while (bl) {
          int src = __ffsll(bl) - 1;
          bl &= bl - 1ull;
          uint32_t kk = (uint32_t)__shfl((int)tkv, src);
          float gc = __shfl(g, src);
          int m = src | (int)((kk & 31u) << 6);
          const float2 cv = ((const float2*)(cw_s + (size_t)m * KDIM))[lane];
          float part = xk0 * cv.x + xk1 * cv.y;
#pragma unroll
          for (int sh = 1; sh < 64; sh <<= 1) part += __shfl_xor(part, sh);
          float p = __expf(part + cb_s[m]) / Dp;
          float sc = p + gc;
          if (sc > bestSc || (sc == bestSc && m < bestM)) { bestSc = sc; bestM = m; }
        }
      }
    }

    float* dst = accum + (size_t)bestM * KDIM + lane * 2;
    atomicAdd(dst + 0, xa.x);
    atomicAdd(dst + 1, xa.y);
  }
}

// ---------------- final: out = accum @ Wd.T + bd ----------------
__global__ void k_final(const float* __restrict__ acc, const float* __restrict__ Wd,
                        const float* __restrict__ bd, float* __restrict__ out) {
  int m = blockIdx.x, j = threadIdx.x;  // 128 threads
  __shared__ float ar[KDIM];
  if (j < 32) ((float4*)ar)[j] = ((const float4*)(acc + (size_t)m * KDIM))[j];
  __syncthreads();
  const float4* wr = (const float4*)(Wd + (size_t)j * KDIM);
  float s = 0.f;
#pragma unroll
  for (int e4 = 0; e4 < 32; ++e4) {
    float4 wv = wr[e4];
    s += wv.x * ar[4 * e4 + 0] + wv.y * ar[4 * e4 + 1]
       + wv.z * ar[4 * e4 + 2] + wv.w * ar[4 * e4 + 3];
  }
  out[(size_t)m * KDIM + j] = s + bd[j];
}

extern "C" void kernel_launch(void* const* d_in, const int* in_sizes, int n_in,
                              void* d_out, int out_size, void* d_ws, size_t ws_size,
                              hipStream_t stream) {
  const float* x1 = (const float*)d_in[0];
  const float* k  = (const float*)d_in[1];
  const float* c  = (const float*)d_in[2];
  const float* Wq = (const float*)d_in[3];
  const float* bq = (const float*)d_in[4];
  const float* Wd = (const float*)d_in[5];
  const float* bd = (const float*)d_in[6];
  float* out = (float*)d_out;

  char* ws = (char*)d_ws;
  size_t off = 0;
  float* cw_s = (float*)(ws + off); off += (size_t)MCOL * KDIM * 4;                   // 1MB
  float* cb_s = (float*)(ws + off); off += 8192;                                      // 8KB
  unsigned short* cwB = (unsigned short*)(ws + off); off += (size_t)MCOL * KDIM * 2;  // 512KB
  float* Wsum = (float*)(ws + off); off += KDIM * KDIM * 4;                           // 64KB
  float* bsum = (float*)(ws + off); off += 4096;
  float* accum = (float*)(ws + off); off += (size_t)MCOL * KDIM * 4;                  // 1MB

  k_wsum<<<64, 256, 0, stream>>>(Wq, bq, Wsum, bsum, accum);
  k_cw<<<MCOL, 128, 0, stream>>>(c, Wsum, bsum, cw_s, cwB, cb_s);
  k_mega<<<2048, 256, 0, stream>>>(x1, k, (const uint4*)cwB, cb_s, cw_s, accum);
  k_final<<<MCOL, 128, 0, stream>>>(accum, Wd, bd, out);
}